// Round 10
// baseline (811.718 us; speedup 1.0000x reference)
//
#include <hip/hip_runtime.h>
#include <hip/hip_bf16.h>

// MultiheadAttention (heads=1 due to reference bug): B=4, N=4096, D=512, PROJ=512.
// scale = 1/sqrt(64) = 0.125. Inputs fp32, output fp32, internal bf16 MFMA.
//
// Pipeline (6 launches on stream):
//  1. transpose_w           Wt[n][k] (bf16) = W[k][n] (fp32) for w_q,w_k,w_v,w_mha
//  2. gemm<1,0,0>           qp = bf16(q) @ Wq + b   (A fp32, fused cast in staging)
//  3. gemm<1,0,0>           kp = bf16(k) @ Wk + b
//  4. gemm<1,1,0>           vpT (fused cast + transposed epilogue)
//  5. flash_attn            dpa = softmax(qp kp^T * 0.125) @ vp
//  6. gemm<0,0,1>           out = dpa @ w_mha + b_mha -> d_out (FP32)
//
// R10 (R9 regressed 352us: 32-key pipeline doubled per-iter merge VALU; reverted).
// Base = R8 (flash 277.5, gemms verified). One change: PV repartitioned to R2's
// correctness-verified e-slice scheme (wave = 64 e-cols x all 4 q-tiles) with V
// read from LDS (not R2's scattered global loads): V LDS reads 256->64KB/iter,
// P reads 16->64KB, net -144KB/iter (-22% of LDS floor). alpha/l broadcast via
// arow/lrowF (R2 logic); rescale moved after barrier B (reads arow, keeps
// __any alpha==1 skip). QKT/softmax/staging/barriers unchanged from R6/R8.
//
// ws layout (shorts): qp, kp, vpT, dpa (8388608 each), Wt (4*262144) = 69 MB.

typedef __attribute__((ext_vector_type(8))) short bf16x8;
typedef __attribute__((ext_vector_type(4))) float f32x4;

#define NB 4
#define NN 4096
#define ND 512

__device__ __forceinline__ f32x4 mfma16(bf16x8 a, bf16x8 b, f32x4 c) {
    return __builtin_amdgcn_mfma_f32_16x16x32_bf16(a, b, c, 0, 0, 0);
}
__device__ __forceinline__ short f2bf(float f) {
    __hip_bfloat16 h = __float2bfloat16(f);
    return *reinterpret_cast<short*>(&h);
}

typedef __attribute__((address_space(1))) const unsigned int gls_gt;
typedef __attribute__((address_space(3))) unsigned int gls_lt;
__device__ __forceinline__ void gll16(const void* g, void* l) {
    __builtin_amdgcn_global_load_lds((gls_gt*)g, (gls_lt*)l, 16, 0, 0);
}

// 16-lane-group reductions on the VALU pipe via DPP row_ror (DPP row = 16 lanes).
#define DPP_ROR_STEP(V, CTRL, OP)                                              \
    {                                                                          \
        int _t = __builtin_amdgcn_update_dpp(0, __float_as_int(V), (CTRL),     \
                                             0xf, 0xf, true);                  \
        (V) = OP((V), __int_as_float(_t));                                     \
    }
__device__ __forceinline__ float faddf(float a, float b) { return a + b; }
__device__ __forceinline__ float rmax16(float v) {
    DPP_ROR_STEP(v, 0x128, fmaxf)
    DPP_ROR_STEP(v, 0x124, fmaxf)
    DPP_ROR_STEP(v, 0x122, fmaxf)
    DPP_ROR_STEP(v, 0x121, fmaxf)
    return v;
}
__device__ __forceinline__ float rsum16(float v) {
    DPP_ROR_STEP(v, 0x128, faddf)
    DPP_ROR_STEP(v, 0x124, faddf)
    DPP_ROR_STEP(v, 0x122, faddf)
    DPP_ROR_STEP(v, 0x121, faddf)
    return v;
}

// ---------------- weight transpose: Wt[c][r] (bf16) = W[r][c] (fp32), 512x512 ----
struct Ptrs4 {
    const float* in[4];
    short* out[4];
};

__global__ void transpose_w(Ptrs4 p) {
    __shared__ short tile[32][33];
    const float* in = p.in[blockIdx.z];
    short* out = p.out[blockIdx.z];
    int r0 = blockIdx.y * 32, c0 = blockIdx.x * 32;
    int tx = threadIdx.x, ty = threadIdx.y;  // 32 x 8
    for (int i = 0; i < 32; i += 8)
        tile[ty + i][tx] = f2bf(in[(r0 + ty + i) * 512 + c0 + tx]);
    __syncthreads();
    for (int i = 0; i < 32; i += 8)
        out[(c0 + ty + i) * 512 + r0 + tx] = tile[tx][ty + i];
}

// ---------------- bt-form GEMM + bias (R8, verified) ----------------------------
template <int AF32, int VT, int OF32>
__global__ __launch_bounds__(256, 2) void gemm_bt_bias(
    const void* __restrict__ Av, const short* __restrict__ Bt,
    const float* __restrict__ bias, void* __restrict__ C) {
    __shared__ __align__(1024) char As[2][16384];
    __shared__ __align__(1024) char Bs[2][16384];
    int tid = threadIdx.x;
    int lane = tid & 63, w = tid >> 6;
    int l15 = lane & 15, l4 = lane >> 4;
    int wr2 = (w & 1) * 64, wc2 = (w >> 1) * 64;
    int m0 = blockIdx.x * 128, n0 = blockIdx.y * 128;
    f32x4 acc[16] = {};  // [mi*4+ni]

    int sr = lane >> 3;
    int sd = ((lane & 7) ^ sr) << 3;  // swizzled k-offset in shorts (gll path)

#define STAGE_B(BUF, KT)                                                    \
    {                                                                       \
        _Pragma("unroll")                                                   \
        for (int i = 0; i < 4; i++) {                                       \
            int rbase = i * 32 + w * 8;                                     \
            gll16(&Bt[(size_t)(n0 + rbase + sr) * 512 + (KT) + sd],         \
                  Bs[BUF] + rbase * 128);                                   \
        }                                                                   \
    }
#define STAGE_A16(BUF, KT)                                                  \
    {                                                                       \
        const short* A16 = (const short*)Av;                                \
        _Pragma("unroll")                                                   \
        for (int i = 0; i < 4; i++) {                                       \
            int rbase = i * 32 + w * 8;                                     \
            gll16(&A16[(size_t)(m0 + rbase + sr) * 512 + (KT) + sd],        \
                  As[BUF] + rbase * 128);                                   \
        }                                                                   \
    }

    float4 areg[8];
    int arow = w * 32 + (lane >> 4);
    int akc = lane & 15;
#define LOAD_A32(KT)                                                        \
    {                                                                       \
        const float* A32 = (const float*)Av;                                \
        _Pragma("unroll")                                                   \
        for (int inst = 0; inst < 8; inst++)                                \
            areg[inst] = ((const float4*)(A32 +                             \
                (size_t)(m0 + arow + inst * 4) * 512 + (KT)))[akc];         \
    }
#define WRITE_A32(BUF)                                                      \
    {                                                                       \
        _Pragma("unroll")                                                   \
        for (int inst = 0; inst < 8; inst++) {                              \
            int r = arow + inst * 4;                                        \
            short pk[4];                                                    \
            pk[0] = f2bf(areg[inst].x); pk[1] = f2bf(areg[inst].y);         \
            pk[2] = f2bf(areg[inst].z); pk[3] = f2bf(areg[inst].w);         \
            *(long long*)(As[BUF] + r * 128 +                               \
                (((akc >> 1) ^ (r & 7)) << 4) + ((akc & 1) << 3)) =         \
                *(const long long*)pk;                                      \
        }                                                                   \
    }

    if (AF32) {
        LOAD_A32(0);
        STAGE_B(0, 0);
        WRITE_A32(0);
    } else {
        STAGE_A16(0, 0);
        STAGE_B(0, 0);
    }
    for (int t = 0; t < 8; t++) {
        __syncthreads();                       // publishes buf[t&1]
        if (t < 7) {
            if (AF32) {
                LOAD_A32((t + 1) * 64);
            } else {
                STAGE_A16((t + 1) & 1, (t + 1) * 64);
            }
            STAGE_B((t + 1) & 1, (t + 1) * 64);
        }
        const char* Ab = As[t & 1];
        const char* Bb = Bs[t & 1];
#pragma unroll
        for (int kb = 0; kb < 2; kb++) {
            int ph = ((((kb << 2) | l4) ^ (l15 & 7)) << 4);
            bf16x8 af[4], bfr[4];
#pragma unroll
            for (int mi = 0; mi < 4; mi++)
                af[mi] = *(const bf16x8*)(Ab + (wr2 + mi * 16 + l15) * 128 + ph);
#pragma unroll
            for (int ni = 0; ni < 4; ni++)
                bfr[ni] = *(const bf16x8*)(Bb + (wc2 + ni * 16 + l15) * 128 + ph);
#pragma unroll
            for (int mi = 0; mi < 4; mi++)
#pragma unroll
                for (int ni = 0; ni < 4; ni++)
                    acc[mi * 4 + ni] = mfma16(af[mi], bfr[ni], acc[mi * 4 + ni]);
        }
        if (AF32 && t < 7) WRITE_A32((t + 1) & 1);   // loads covered by MFMA phase
    }
#undef STAGE_B
#undef STAGE_A16
#undef LOAD_A32
#undef WRITE_A32
    if (OF32) {
        for (int mi = 0; mi < 4; mi++)
            for (int ni = 0; ni < 4; ni++) {
                f32x4 vv = acc[mi * 4 + ni];
                int col = n0 + wc2 + ni * 16 + l15;
                float bv = bias[col];
                for (int r = 0; r < 4; r++) {
                    int row = m0 + wr2 + mi * 16 + l4 * 4 + r;
                    ((float*)C)[(size_t)row * 512 + col] = vv[r] + bv;
                }
            }
    } else if (VT) {
        __syncthreads();
        short* Ct = (short*)As;
#pragma unroll
        for (int mi = 0; mi < 4; mi++)
#pragma unroll
            for (int ni = 0; ni < 4; ni++) {
                f32x4 vv = acc[mi * 4 + ni];
                int col = wc2 + ni * 16 + l15;
                float bv = bias[n0 + col];
                int r0w = wr2 + mi * 16 + l4 * 4;
                short pk[4];
#pragma unroll
                for (int r = 0; r < 4; r++) pk[r] = f2bf(vv[r] + bv);
                int byteoff = col * 256 + ((r0w * 2) ^ ((col & 7) << 4));
                *(long long*)((char*)Ct + byteoff) = *(const long long*)pk;
            }
        __syncthreads();
        int b = m0 >> 12;
        short* Cb = (short*)C + (size_t)b * (ND * NN) + (m0 & 4095);
#pragma unroll
        for (int s = 0; s < 8; s++) {
            int col = (tid >> 4) + 16 * s;
            int j = tid & 15;
            int byteoff = col * 256 + ((16 * j) ^ ((col & 7) << 4));
            bf16x8 vvv = *(const bf16x8*)((char*)Ct + byteoff);
            *(bf16x8*)(Cb + (size_t)(n0 + col) * NN + 8 * j) = vvv;
        }
    } else {
        __syncthreads();
        short* Ct = (short*)As;
#pragma unroll
        for (int mi = 0; mi < 4; mi++)
#pragma unroll
            for (int ni = 0; ni < 4; ni++) {
                f32x4 vv = acc[mi * 4 + ni];
                int col = wc2 + ni * 16 + l15;
                float bv = bias[n0 + col];
#pragma unroll
                for (int r = 0; r < 4; r++) {
                    int row = wr2 + mi * 16 + l4 * 4 + r;
                    int byteoff = row * 256 + ((col * 2) ^ ((row & 3) << 5));
                    *(short*)((char*)Ct + byteoff) = f2bf(vv[r] + bv);
                }
            }
        __syncthreads();
#pragma unroll
        for (int s = 0; s < 8; s++) {
            int row = (tid >> 4) + 16 * s;
            int j = tid & 15;
            int byteoff = row * 256 + ((16 * j) ^ ((row & 3) << 5));
            bf16x8 vvv = *(const bf16x8*)((char*)Ct + byteoff);
            *(bf16x8*)((short*)C + (size_t)(m0 + row) * 512 + n0 + 8 * j) = vvv;
        }
    }
}

// ---------------- flash attention (R6 base + R2-verified e-slice PV) ------------
// Block: 64 Q-rows of one batch, 512 threads (8 waves).
// QKT/softmax partition: wr = w&3 q-16-block, wc = w>>2 key-half (unchanged).
// PV partition (R2, verified): wave w owns e-slice [w*64, w*64+64), all 4
// q-tiles; V frags from LDS (1 wave per frag -> 4x fewer V reads).
// LDS 140 KB: Ks 64KB (slot^(key&15)), Vs 64KB (slot^(e&7)), Pld 8KB
// (slot^(row&7)), Sex/arow/lrowF stats. 3 barriers/iter, stages prefetched.
__global__ __launch_bounds__(512, 2) void flash_attn(
    const short* __restrict__ qp, const short* __restrict__ kp,
    const short* __restrict__ vpT, short* __restrict__ dpa) {
    __shared__ __align__(1024) char KsB[65536];
    __shared__ __align__(1024) char VsB[65536];
    __shared__ __align__(16)   char PldB[8192];
    __shared__ float SexM[128];   // [wc][row] half-max
    __shared__ float SexS[128];   // [wc][row] half-sum
    __shared__ float arow[64];    // per-iter alpha (1.0 when max unchanged)
    __shared__ float lrowF[64];   // final l per row

    int tid = threadIdx.x;
    int lane = tid & 63, w = tid >> 6;
    int l15 = lane & 15, l4 = lane >> 4;
    int wr = w & 3;    // q 16-row block (QKT/softmax role)
    int wc = w >> 2;   // key half      (QKT/softmax role)
    int e0 = w * 64;   // e-slice       (PV role)
    int b = blockIdx.y;
    int q0 = blockIdx.x * 64;

    const short* qpb = qp + b * (NN * ND);
    const short* kpb = kp + b * (NN * ND);
    const short* vtb = vpT + b * (ND * NN);

    // persistent Q fragments: A-row = l15 (q-row q0+wr*16+l15), k = kb*32 + l4*8
    bf16x8 qf[16];
    {
        const short* qrow = qpb + (q0 + wr * 16 + l15) * ND + l4 * 8;
#pragma unroll
        for (int kb = 0; kb < 16; kb++) qf[kb] = *(const bf16x8*)(qrow + kb * 32);
    }
    f32x4 oacc[16] = {};   // [qt*4+et]: row qt*16+l4*4+r, col e0+et*16+l15
    float m_run[4], l_run[4];
#pragma unroll
    for (int r = 0; r < 4; r++) { m_run[r] = -1e30f; l_run[r] = 0.f; }

    // K row r (1024B): physical slot p holds logical 16B chunk d = p ^ (r&15).
#define STAGE_K(J0)                                                         \
    {                                                                       \
        _Pragma("unroll")                                                   \
        for (int c = 0; c < 8; c++) {                                       \
            int key = w * 8 + c;                                            \
            const short* src = kpb + (size_t)((J0) + key) * ND +            \
                               ((lane ^ (key & 15)) << 3);                  \
            gll16(src, KsB + key * 1024);                                   \
        }                                                                   \
    }
    // V e-row (128B, 8 slots): slot p holds chunk p ^ (e&7). One gll = 8 e-rows.
#define STAGE_V(J0)                                                         \
    {                                                                       \
        _Pragma("unroll")                                                   \
        for (int c = 0; c < 8; c++) {                                       \
            int g = w * 8 + c;                                              \
            int e = g * 8 + (lane >> 3);                                    \
            const short* src = vtb + (size_t)e * NN + (J0) +                \
                               (((lane & 7) ^ (e & 7)) << 3);               \
            gll16(src, VsB + g * 1024);                                     \
        }                                                                   \
    }

    STAGE_K(0);
    STAGE_V(0);
    __syncthreads();

    for (int j0 = 0; j0 < NN; j0 += 64) {
        // ---- S = Q K^T : C[m=q (l4*4+r)][n=key (l15)], keys wc*32 + t*16 + l15 ----
        f32x4 s0 = {}, s1 = {};
        {
            const char* kb0 = KsB + (32 * wc + l15) * 1024;
            const char* kb1 = kb0 + 16 * 1024;
#pragma unroll
            for (int kb = 0; kb < 16; kb++) {
                int sl = ((((kb << 2) | l4) ^ l15) << 4);   // (key&15)==l15 for both tiles
                s0 = mfma16(qf[kb], *(const bf16x8*)(kb0 + sl), s0);
                s1 = mfma16(qf[kb], *(const bf16x8*)(kb1 + sl), s1);
            }
        }
        // ---- in-register half softmax stats (over this wc's 32 keys) ----
        float vv0[4], vv1[4], mx[4], ss[4], p0[4], p1[4];
#pragma unroll
        for (int r = 0; r < 4; r++) {
            vv0[r] = s0[r] * 0.125f;
            vv1[r] = s1[r] * 0.125f;
            mx[r] = rmax16(fmaxf(vv0[r], vv1[r]));
        }
#pragma unroll
        for (int r = 0; r < 4; r++) {
            p0[r] = __expf(vv0[r] - mx[r]);
            p1[r] = __expf(vv1[r] - mx[r]);
            ss[r] = rsum16(p0[r] + p1[r]);
        }
        int row4 = wr * 16 + l4 * 4;
        if (l15 == 0) {
#pragma unroll
            for (int r = 0; r < 4; r++) {
                SexM[wc * 64 + row4 + r] = mx[r];
                SexS[wc * 64 + row4 + r] = ss[r];
            }
        }
        __syncthreads();   // A: Sex visible; V(t) stage drained
        // ---- merge halves, running (m,l) update, write P bf16 + alpha ----
#pragma unroll
        for (int r = 0; r < 4; r++) {
            int row = row4 + r;
            float mo = SexM[(wc ^ 1) * 64 + row];
            float so = SexS[(wc ^ 1) * 64 + row];
            float mt = fmaxf(mx[r], mo);
            float st = ss[r] * __expf(mx[r] - mt) + so * __expf(mo - mt);
            float mn = fmaxf(m_run[r], mt);
            float al = __expf(m_run[r] - mn);
            l_run[r] = l_run[r] * al + st * __expf(mt - mn);
            m_run[r] = mn;
            float fs = __expf(mx[r] - mn);
            if (wc == 0 && l15 == 0) arow[row] = al;
            int rw7 = row & 7;
            char* prow = PldB + row * 128;
            int col0 = wc * 32 + l15;
            *(short*)(prow + (((col0 >> 3) ^ rw7) << 4) + ((col0 & 7) << 1)) = f2bf(p0[r] * fs);
            int col1 = col0 + 16;
            *(short*)(prow + (((col1 >> 3) ^ rw7) << 4) + ((col1 & 7) << 1)) = f2bf(p1[r] * fs);
        }
        __syncthreads();   // B: Pld + arow visible
        if (j0 + 64 < NN) STAGE_K(j0 + 64);   // lands during PV, drains at barrier C
        // ---- O rescale (all 4 q-tiles), skipped when alpha==1 everywhere ----
        {
            float alq[4][4];
            bool need = false;
#pragma unroll
            for (int qt = 0; qt < 4; qt++)
#pragma unroll
                for (int r = 0; r < 4; r++) {
                    alq[qt][r] = arow[qt * 16 + l4 * 4 + r];
                    need |= (alq[qt][r] != 1.0f);
                }
            if (__any(need)) {
#pragma unroll
                for (int qt = 0; qt < 4; qt++)
#pragma unroll
                    for (int et = 0; et < 4; et++)
#pragma unroll
                        for (int r = 0; r < 4; r++)
                            oacc[qt * 4 + et][r] *= alq[qt][r];
            }
        }
        // ---- O += P V over this wave's e-slice (V from LDS, 1 wave/frag) ----
        bf16x8 pa[8];   // [qt*2+jb]: P rows qt*16+l15, keys jb*32+l4*8
        bf16x8 vf[8];   // [et*2+jb]: V e-row e0+et*16+l15, keys jb*32+l4*8
        {
            int sw = l15 & 7;
#pragma unroll
            for (int qt = 0; qt < 4; qt++) {
                const char* prow = PldB + (qt * 16 + l15) * 128;
#pragma unroll
                for (int jb = 0; jb < 2; jb++)
                    pa[qt * 2 + jb] = *(const bf16x8*)(prow + (((jb * 4 + l4) ^ sw) << 4));
            }
#pragma unroll
            for (int et = 0; et < 4; et++) {
                const char* vrow = VsB + (e0 + et * 16 + l15) * 128;   // (e&7)==sw
#pragma unroll
                for (int jb = 0; jb < 2; jb++)
                    vf[et * 2 + jb] = *(const bf16x8*)(vrow + (((jb * 4 + l4) ^ sw) << 4));
            }
        }
#pragma unroll
        for (int qt = 0; qt < 4; qt++)
#pragma unroll
            for (int et = 0; et < 4; et++) {
                int oi = qt * 4 + et;
                oacc[oi] = mfma16(pa[qt * 2 + 0], vf[et * 2 + 0], oacc[oi]);
                oacc[oi] = mfma16(pa[qt * 2 + 1], vf[et * 2 + 1], oacc[oi]);
            }
        __syncthreads();   // C: PV reads done; K(t+1) drained
        if (j0 + 64 < NN) STAGE_V(j0 + 64);   // lands during next QK^T, drains at A
    }
    // ---- finalize: publish l, O /= l, store dpa by e-slice ----
    if (wc == 0 && l15 == 0) {
#pragma unroll
        for (int r = 0; r < 4; r++) lrowF[wr * 16 + l4 * 4 + r] = l_run[r];
    }
    __syncthreads();
    short* dpb = dpa + b * (NN * ND);
#pragma unroll
    for (int qt = 0; qt < 4; qt++) {
        float li[4];
#pragma unroll
        for (int r = 0; r < 4; r++) li[r] = 1.f / lrowF[qt * 16 + l4 * 4 + r];
#pragma unroll
        for (int et = 0; et < 4; et++) {
            int col = e0 + et * 16 + l15;
#pragma unroll
            for (int r = 0; r < 4; r++) {
                int row = q0 + qt * 16 + l4 * 4 + r;
                dpb[row * ND + col] = f2bf(oacc[qt * 4 + et][r] * li[r]);
            }
        }
    }
}

extern "C" void kernel_launch(void* const* d_in, const int* in_sizes, int n_in,
                              void* d_out, int out_size, void* d_ws, size_t ws_size,
                              hipStream_t stream) {
    const float* q     = (const float*)d_in[0];
    const float* k     = (const float*)d_in[1];
    const float* v     = (const float*)d_in[2];
    const float* w_q   = (const float*)d_in[3];
    const float* w_k   = (const float*)d_in[4];
    const float* w_v   = (const float*)d_in[5];
    const float* w_mha = (const float*)d_in[6];
    const float* b_q   = (const float*)d_in[7];
    const float* b_k   = (const float*)d_in[8];
    const float* b_v   = (const float*)d_in[9];
    const float* b_mha = (const float*)d_in[10];

    const size_t T = (size_t)NB * NN * ND;  // 8388608
    short* ws  = (short*)d_ws;
    short* qp  = ws;
    short* kp  = qp + T;
    short* vpT = kp + T;
    short* dpa = vpT + T;
    short* Wt  = dpa + T;  // 4 * 262144 shorts

    Ptrs4 p;
    p.in[0] = w_q;   p.out[0] = Wt;
    p.in[1] = w_k;   p.out[1] = Wt + 262144;
    p.in[2] = w_v;   p.out[2] = Wt + 524288;
    p.in[3] = w_mha; p.out[3] = Wt + 786432;
    transpose_w<<<dim3(16, 16, 4), dim3(32, 8), 0, stream>>>(p);

    gemm_bt_bias<1, 0, 0><<<dim3(128, 4), 256, 0, stream>>>(q, Wt,          b_q, qp);
    gemm_bt_bias<1, 0, 0><<<dim3(128, 4), 256, 0, stream>>>(k, Wt + 262144, b_k, kp);
    gemm_bt_bias<1, 1, 0><<<dim3(128, 4), 256, 0, stream>>>(v, Wt + 524288, b_v, vpT);

    flash_attn<<<dim3(64, 4), 512, 0, stream>>>(qp, kp, vpT, dpa);

    gemm_bt_bias<0, 0, 1><<<dim3(128, 4), 256, 0, stream>>>(dpa, Wt + 786432, b_mha, d_out);
}

// Round 11
// 461.189 us; speedup vs baseline: 1.7601x; 1.7601x over previous
//
#include <hip/hip_runtime.h>
#include <hip/hip_bf16.h>

// MultiheadAttention (heads=1 due to reference bug): B=4, N=4096, D=512, PROJ=512.
// scale = 1/sqrt(64) = 0.125. Inputs fp32, output fp32, internal bf16 MFMA.
//
// Pipeline (6 launches on stream):
//  1. transpose_w           Wt[n][k] (bf16) = W[k][n] (fp32) for w_q,w_k,w_v,w_mha
//  2. gemm<1,0,0>           qp = bf16(q) @ Wq + b   (A fp32, fused cast in staging)
//  3. gemm<1,0,0>           kp = bf16(k) @ Wk + b
//  4. gemm<1,1,0>           vpT (fused cast + transposed epilogue)
//  5. flash_attn            dpa = softmax(qp kp^T * 0.125) @ vp
//  6. gemm<0,0,1>           out = dpa @ w_mha + b_mha -> d_out (FP32)
//
// R11 = revert to R8 (verified 464.2us; flash 277.5). R9 (32-key pipeline)
// regressed -27% (per-iter merge VALU doubled with iteration count); R10
// (e-slice PV from LDS) regressed -56% (PV working set ~210 regs > 128 cap ->
// scratch spills, WRITE_SIZE 21->335MB). Flash's remaining 2x over its ~138us
// LDS floor is the phase-serial barrier structure; both validated escape routes
// failed on hardware, so R8 stands as the session deliverable.
//
// R8 contents: flash = R6 structure (full-chunk swizzled K/V via global_load_lds,
// DPP row_ror softmax on VALU pipe, alpha==1 rescale skip, 3 barriers/iter,
// 0 bank conflicts); GEMMs = 128x128 tile dbuf gll16 staging, fused fp32->bf16
// A-cast (reg-stage + swizzled ds_write), XCD-aware grid (128,4), LDS epilogues.
//
// ws layout (shorts): qp, kp, vpT, dpa (8388608 each), Wt (4*262144) = 69 MB.

typedef __attribute__((ext_vector_type(8))) short bf16x8;
typedef __attribute__((ext_vector_type(4))) float f32x4;

#define NB 4
#define NN 4096
#define ND 512

__device__ __forceinline__ f32x4 mfma16(bf16x8 a, bf16x8 b, f32x4 c) {
    return __builtin_amdgcn_mfma_f32_16x16x32_bf16(a, b, c, 0, 0, 0);
}
__device__ __forceinline__ short f2bf(float f) {
    __hip_bfloat16 h = __float2bfloat16(f);
    return *reinterpret_cast<short*>(&h);
}

typedef __attribute__((address_space(1))) const unsigned int gls_gt;
typedef __attribute__((address_space(3))) unsigned int gls_lt;
__device__ __forceinline__ void gll16(const void* g, void* l) {
    __builtin_amdgcn_global_load_lds((gls_gt*)g, (gls_lt*)l, 16, 0, 0);
}

// 16-lane-group reductions on the VALU pipe via DPP row_ror (DPP row = 16 lanes).
#define DPP_ROR_STEP(V, CTRL, OP)                                              \
    {                                                                          \
        int _t = __builtin_amdgcn_update_dpp(0, __float_as_int(V), (CTRL),     \
                                             0xf, 0xf, true);                  \
        (V) = OP((V), __int_as_float(_t));                                     \
    }
__device__ __forceinline__ float faddf(float a, float b) { return a + b; }
__device__ __forceinline__ float rmax16(float v) {
    DPP_ROR_STEP(v, 0x128, fmaxf)
    DPP_ROR_STEP(v, 0x124, fmaxf)
    DPP_ROR_STEP(v, 0x122, fmaxf)
    DPP_ROR_STEP(v, 0x121, fmaxf)
    return v;
}
__device__ __forceinline__ float rsum16(float v) {
    DPP_ROR_STEP(v, 0x128, faddf)
    DPP_ROR_STEP(v, 0x124, faddf)
    DPP_ROR_STEP(v, 0x122, faddf)
    DPP_ROR_STEP(v, 0x121, faddf)
    return v;
}

// ---------------- weight transpose: Wt[c][r] (bf16) = W[r][c] (fp32), 512x512 ----
struct Ptrs4 {
    const float* in[4];
    short* out[4];
};

__global__ void transpose_w(Ptrs4 p) {
    __shared__ short tile[32][33];
    const float* in = p.in[blockIdx.z];
    short* out = p.out[blockIdx.z];
    int r0 = blockIdx.y * 32, c0 = blockIdx.x * 32;
    int tx = threadIdx.x, ty = threadIdx.y;  // 32 x 8
    for (int i = 0; i < 32; i += 8)
        tile[ty + i][tx] = f2bf(in[(r0 + ty + i) * 512 + c0 + tx]);
    __syncthreads();
    for (int i = 0; i < 32; i += 8)
        out[(c0 + ty + i) * 512 + r0 + tx] = tile[tx][ty + i];
}

// ---------------- bt-form GEMM + bias: C[m][n] = sum_k A[m][k]*Bt[n][k] + bias[n] ----
// K = N = 512. 128x128 tile, 256 threads (4 waves), wave = 64x64 quadrant (4x4
// frags). B staged via global_load_lds w=16 + XOR swizzle (16B slot p of row r
// holds chunk p^(r&7)), dbuf. A: AF32 -> fp32 reg-staged (dwordx4 + f2bf +
// swizzled ds_write_b64, loads early / writes post-MFMA); else gll16 like B.
// Grid (128,4): x = m-tile (same-A blocks 128 apart -> same XCD), y = n-tile.
// VT: per-batch transposed C_T[b][n][j] via LDS retile; OF32: fp32 out.
template <int AF32, int VT, int OF32>
__global__ __launch_bounds__(256, 2) void gemm_bt_bias(
    const void* __restrict__ Av, const short* __restrict__ Bt,
    const float* __restrict__ bias, void* __restrict__ C) {
    __shared__ __align__(1024) char As[2][16384];
    __shared__ __align__(1024) char Bs[2][16384];
    int tid = threadIdx.x;
    int lane = tid & 63, w = tid >> 6;
    int l15 = lane & 15, l4 = lane >> 4;
    int wr2 = (w & 1) * 64, wc2 = (w >> 1) * 64;
    int m0 = blockIdx.x * 128, n0 = blockIdx.y * 128;
    f32x4 acc[16] = {};  // [mi*4+ni]

    int sr = lane >> 3;
    int sd = ((lane & 7) ^ sr) << 3;  // swizzled k-offset in shorts (gll path)

#define STAGE_B(BUF, KT)                                                    \
    {                                                                       \
        _Pragma("unroll")                                                   \
        for (int i = 0; i < 4; i++) {                                       \
            int rbase = i * 32 + w * 8;                                     \
            gll16(&Bt[(size_t)(n0 + rbase + sr) * 512 + (KT) + sd],         \
                  Bs[BUF] + rbase * 128);                                   \
        }                                                                   \
    }
#define STAGE_A16(BUF, KT)                                                  \
    {                                                                       \
        const short* A16 = (const short*)Av;                                \
        _Pragma("unroll")                                                   \
        for (int i = 0; i < 4; i++) {                                       \
            int rbase = i * 32 + w * 8;                                     \
            gll16(&A16[(size_t)(m0 + rbase + sr) * 512 + (KT) + sd],        \
                  As[BUF] + rbase * 128);                                   \
        }                                                                   \
    }

    float4 areg[8];
    int arow = w * 32 + (lane >> 4);
    int akc = lane & 15;
#define LOAD_A32(KT)                                                        \
    {                                                                       \
        const float* A32 = (const float*)Av;                                \
        _Pragma("unroll")                                                   \
        for (int inst = 0; inst < 8; inst++)                                \
            areg[inst] = ((const float4*)(A32 +                             \
                (size_t)(m0 + arow + inst * 4) * 512 + (KT)))[akc];         \
    }
#define WRITE_A32(BUF)                                                      \
    {                                                                       \
        _Pragma("unroll")                                                   \
        for (int inst = 0; inst < 8; inst++) {                              \
            int r = arow + inst * 4;                                        \
            short pk[4];                                                    \
            pk[0] = f2bf(areg[inst].x); pk[1] = f2bf(areg[inst].y);         \
            pk[2] = f2bf(areg[inst].z); pk[3] = f2bf(areg[inst].w);         \
            *(long long*)(As[BUF] + r * 128 +                               \
                (((akc >> 1) ^ (r & 7)) << 4) + ((akc & 1) << 3)) =         \
                *(const long long*)pk;                                      \
        }                                                                   \
    }

    if (AF32) {
        LOAD_A32(0);
        STAGE_B(0, 0);
        WRITE_A32(0);
    } else {
        STAGE_A16(0, 0);
        STAGE_B(0, 0);
    }
    for (int t = 0; t < 8; t++) {
        __syncthreads();                       // publishes buf[t&1]
        if (t < 7) {
            if (AF32) {
                LOAD_A32((t + 1) * 64);
            } else {
                STAGE_A16((t + 1) & 1, (t + 1) * 64);
            }
            STAGE_B((t + 1) & 1, (t + 1) * 64);
        }
        const char* Ab = As[t & 1];
        const char* Bb = Bs[t & 1];
#pragma unroll
        for (int kb = 0; kb < 2; kb++) {
            int ph = ((((kb << 2) | l4) ^ (l15 & 7)) << 4);
            bf16x8 af[4], bfr[4];
#pragma unroll
            for (int mi = 0; mi < 4; mi++)
                af[mi] = *(const bf16x8*)(Ab + (wr2 + mi * 16 + l15) * 128 + ph);
#pragma unroll
            for (int ni = 0; ni < 4; ni++)
                bfr[ni] = *(const bf16x8*)(Bb + (wc2 + ni * 16 + l15) * 128 + ph);
#pragma unroll
            for (int mi = 0; mi < 4; mi++)
#pragma unroll
                for (int ni = 0; ni < 4; ni++)
                    acc[mi * 4 + ni] = mfma16(af[mi], bfr[ni], acc[mi * 4 + ni]);
        }
        if (AF32 && t < 7) WRITE_A32((t + 1) & 1);   // loads covered by MFMA phase
    }
#undef STAGE_B
#undef STAGE_A16
#undef LOAD_A32
#undef WRITE_A32
    if (OF32) {
        for (int mi = 0; mi < 4; mi++)
            for (int ni = 0; ni < 4; ni++) {
                f32x4 vv = acc[mi * 4 + ni];
                int col = n0 + wc2 + ni * 16 + l15;
                float bv = bias[col];
                for (int r = 0; r < 4; r++) {
                    int row = m0 + wr2 + mi * 16 + l4 * 4 + r;
                    ((float*)C)[(size_t)row * 512 + col] = vv[r] + bv;
                }
            }
    } else if (VT) {
        __syncthreads();
        short* Ct = (short*)As;
#pragma unroll
        for (int mi = 0; mi < 4; mi++)
#pragma unroll
            for (int ni = 0; ni < 4; ni++) {
                f32x4 vv = acc[mi * 4 + ni];
                int col = wc2 + ni * 16 + l15;
                float bv = bias[n0 + col];
                int r0w = wr2 + mi * 16 + l4 * 4;
                short pk[4];
#pragma unroll
                for (int r = 0; r < 4; r++) pk[r] = f2bf(vv[r] + bv);
                int byteoff = col * 256 + ((r0w * 2) ^ ((col & 7) << 4));
                *(long long*)((char*)Ct + byteoff) = *(const long long*)pk;
            }
        __syncthreads();
        int b = m0 >> 12;
        short* Cb = (short*)C + (size_t)b * (ND * NN) + (m0 & 4095);
#pragma unroll
        for (int s = 0; s < 8; s++) {
            int col = (tid >> 4) + 16 * s;
            int j = tid & 15;
            int byteoff = col * 256 + ((16 * j) ^ ((col & 7) << 4));
            bf16x8 vvv = *(const bf16x8*)((char*)Ct + byteoff);
            *(bf16x8*)(Cb + (size_t)(n0 + col) * NN + 8 * j) = vvv;
        }
    } else {
        __syncthreads();
        short* Ct = (short*)As;
#pragma unroll
        for (int mi = 0; mi < 4; mi++)
#pragma unroll
            for (int ni = 0; ni < 4; ni++) {
                f32x4 vv = acc[mi * 4 + ni];
                int col = wc2 + ni * 16 + l15;
                float bv = bias[n0 + col];
#pragma unroll
                for (int r = 0; r < 4; r++) {
                    int row = wr2 + mi * 16 + l4 * 4 + r;
                    int byteoff = row * 256 + ((col * 2) ^ ((row & 3) << 5));
                    *(short*)((char*)Ct + byteoff) = f2bf(vv[r] + bv);
                }
            }
        __syncthreads();
#pragma unroll
        for (int s = 0; s < 8; s++) {
            int row = (tid >> 4) + 16 * s;
            int j = tid & 15;
            int byteoff = row * 256 + ((16 * j) ^ ((row & 3) << 5));
            bf16x8 vvv = *(const bf16x8*)((char*)Ct + byteoff);
            *(bf16x8*)((short*)C + (size_t)(m0 + row) * 512 + n0 + 8 * j) = vvv;
        }
    }
}

// ---------------- flash attention (R6/R8 structure, verified @276-278us) --------
// Block: 64 Q-rows of one batch, 512 threads (8 waves: wr 0..3 q-16-blocks x wc 0..1
// key/e-halves). Q persistent in regs. Full 64-key chunk staged per iteration.
// LDS 140 KB (1 block/CU): Ks 64x512 bf16 (slot^row&15), Vs 512x64 bf16 (slot^row&7),
// Pld 64x64 bf16 (slot^row&7), Sex stats. 3 barriers/iter, both stages prefetched.
__global__ __launch_bounds__(512, 2) void flash_attn(
    const short* __restrict__ qp, const short* __restrict__ kp,
    const short* __restrict__ vpT, short* __restrict__ dpa) {
    __shared__ __align__(1024) char KsB[65536];
    __shared__ __align__(1024) char VsB[65536];
    __shared__ __align__(16)   char PldB[8192];
    __shared__ float SexM[128];   // [wc][row] half-max
    __shared__ float SexS[128];   // [wc][row] half-sum

    int tid = threadIdx.x;
    int lane = tid & 63, w = tid >> 6;
    int l15 = lane & 15, l4 = lane >> 4;
    int wr = w & 3;    // q 16-row block
    int wc = w >> 2;   // key/e half
    int b = blockIdx.y;
    int q0 = blockIdx.x * 64;

    const short* qpb = qp + b * (NN * ND);
    const short* kpb = kp + b * (NN * ND);
    const short* vtb = vpT + b * (ND * NN);

    // persistent Q fragments: A-row = l15 (q-row q0+wr*16+l15), k = kb*32 + l4*8
    bf16x8 qf[16];
    {
        const short* qrow = qpb + (q0 + wr * 16 + l15) * ND + l4 * 8;
#pragma unroll
        for (int kb = 0; kb < 16; kb++) qf[kb] = *(const bf16x8*)(qrow + kb * 32);
    }
    f32x4 oacc[16] = {};
    float m_run[4], l_run[4];
#pragma unroll
    for (int r = 0; r < 4; r++) { m_run[r] = -1e30f; l_run[r] = 0.f; }

    // swizzled 16B-slot byte offsets for V/P reads (row&7 == l15&7 on all read rows)
    const int vsl0 = ((l4 ^ (l15 & 7)) << 4);
    const int vsl1 = vsl0 ^ 64;

    // K row r (1024B): physical slot p holds logical 16B chunk d = p ^ (r&15).
#define STAGE_K(J0)                                                         \
    {                                                                       \
        _Pragma("unroll")                                                   \
        for (int c = 0; c < 8; c++) {                                       \
            int key = w * 8 + c;                                            \
            const short* src = kpb + (size_t)((J0) + key) * ND +            \
                               ((lane ^ (key & 15)) << 3);                  \
            gll16(src, KsB + key * 1024);                                   \
        }                                                                   \
    }
    // V e-row (128B, 8 slots): slot p holds chunk p ^ (e&7). One gll = 8 e-rows.
#define STAGE_V(J0)                                                         \
    {                                                                       \
        _Pragma("unroll")                                                   \
        for (int c = 0; c < 8; c++) {                                       \
            int g = w * 8 + c;                                              \
            int e = g * 8 + (lane >> 3);                                    \
            const short* src = vtb + (size_t)e * NN + (J0) +                \
                               (((lane & 7) ^ (e & 7)) << 3);               \
            gll16(src, VsB + g * 1024);                                     \
        }                                                                   \
    }

    STAGE_K(0);
    STAGE_V(0);
    __syncthreads();

    for (int j0 = 0; j0 < NN; j0 += 64) {
        // ---- S = Q K^T : C[m=q (l4*4+r)][n=key (l15)], keys wc*32 + t*16 + l15 ----
        f32x4 s0 = {}, s1 = {};
        {
            const char* kb0 = KsB + (32 * wc + l15) * 1024;
            const char* kb1 = kb0 + 16 * 1024;
#pragma unroll
            for (int kb = 0; kb < 16; kb++) {
                int sl = ((((kb << 2) | l4) ^ l15) << 4);   // (key&15)==l15 for both tiles
                s0 = mfma16(qf[kb], *(const bf16x8*)(kb0 + sl), s0);
                s1 = mfma16(qf[kb], *(const bf16x8*)(kb1 + sl), s1);
            }
        }
        // ---- in-register half softmax stats (over this wc's 32 keys) ----
        // 16-lane reductions on VALU via DPP row_ror (no LDS traffic)
        float vv0[4], vv1[4], mx[4], ss[4], p0[4], p1[4];
#pragma unroll
        for (int r = 0; r < 4; r++) {
            vv0[r] = s0[r] * 0.125f;
            vv1[r] = s1[r] * 0.125f;
            mx[r] = rmax16(fmaxf(vv0[r], vv1[r]));
        }
#pragma unroll
        for (int r = 0; r < 4; r++) {
            p0[r] = __expf(vv0[r] - mx[r]);
            p1[r] = __expf(vv1[r] - mx[r]);
            ss[r] = rsum16(p0[r] + p1[r]);
        }
        int row4 = wr * 16 + l4 * 4;
        if (l15 == 0) {
#pragma unroll
            for (int r = 0; r < 4; r++) {
                SexM[wc * 64 + row4 + r] = mx[r];
                SexS[wc * 64 + row4 + r] = ss[r];
            }
        }
        __syncthreads();   // A: Sex visible; V(t) stage drained
        // ---- merge halves, running (m,l) update, write P bf16 ----
        float al4[4];
#pragma unroll
        for (int r = 0; r < 4; r++) {
            int row = row4 + r;
            float mo = SexM[(wc ^ 1) * 64 + row];
            float so = SexS[(wc ^ 1) * 64 + row];
            float mt = fmaxf(mx[r], mo);
            float st = ss[r] * __expf(mx[r] - mt) + so * __expf(mo - mt);
            float mn = fmaxf(m_run[r], mt);
            float al = __expf(m_run[r] - mn);
            l_run[r] = l_run[r] * al + st * __expf(mt - mn);
            m_run[r] = mn;
            al4[r] = al;
            float fs = __expf(mx[r] - mn);
            int rw7 = row & 7;
            char* prow = PldB + row * 128;
            int col0 = wc * 32 + l15;
            *(short*)(prow + (((col0 >> 3) ^ rw7) << 4) + ((col0 & 7) << 1)) = f2bf(p0[r] * fs);
            int col1 = col0 + 16;
            *(short*)(prow + (((col1 >> 3) ^ rw7) << 4) + ((col1 & 7) << 1)) = f2bf(p1[r] * fs);
        }
        // ---- O rescale, skipped when alpha==1 for all 16 rows of this wave
        // (exact: __expf(0)==1.0f when running max unchanged) ----
        {
            bool need = (al4[0] != 1.f) | (al4[1] != 1.f) |
                        (al4[2] != 1.f) | (al4[3] != 1.f);
            if (__any(need)) {
#pragma unroll
                for (int t = 0; t < 16; t++)
#pragma unroll
                    for (int r = 0; r < 4; r++) oacc[t][r] *= al4[r];
            }
        }
        __syncthreads();   // B: Pld visible
        if (j0 + 64 < NN) STAGE_K(j0 + 64);   // lands during PV, drains at barrier C
        // ---- O += P V ----
        bf16x8 pa0, pa1;
        {
            const char* prow = PldB + (wr * 16 + l15) * 128;
            pa0 = *(const bf16x8*)(prow + vsl0);   // keys 0..31  (chunk l4)
            pa1 = *(const bf16x8*)(prow + vsl1);   // keys 32..63 (chunk 4+l4)
        }
#pragma unroll
        for (int eh = 0; eh < 2; eh++) {
#pragma unroll
            for (int i = 0; i < 8; i++) {
                const char* vb = VsB + (eh * 256 + 32 * i + 16 * wc + l15) * 128;
                int oi = eh * 8 + i;
                oacc[oi] = mfma16(pa0, *(const bf16x8*)(vb + vsl0), oacc[oi]);
                oacc[oi] = mfma16(pa1, *(const bf16x8*)(vb + vsl1), oacc[oi]);
            }
        }
        __syncthreads();   // C: PV done; K(t+1) drained
        if (j0 + 64 < NN) STAGE_V(j0 + 64);   // lands during next QK^T, drains at A
    }
    // ---- finalize: O /= l, store dpa ----
    float li[4];
#pragma unroll
    for (int r = 0; r < 4; r++) li[r] = 1.f / l_run[r];
    short* dpb = dpa + b * (NN * ND);
#pragma unroll
    for (int eh = 0; eh < 2; eh++)
#pragma unroll
        for (int i = 0; i < 8; i++) {
            int col = (16 * eh + 2 * i + wc) * 16 + l15;
#pragma unroll
            for (int r = 0; r < 4; r++) {
                int row = q0 + wr * 16 + l4 * 4 + r;
                dpb[row * ND + col] = f2bf(oacc[eh * 8 + i][r] * li[r]);
            }
        }
}

extern "C" void kernel_launch(void* const* d_in, const int* in_sizes, int n_in,
                              void* d_out, int out_size, void* d_ws, size_t ws_size,
                              hipStream_t stream) {
    const float* q     = (const float*)d_in[0];
    const float* k     = (const float*)d_in[1];
    const float* v     = (const float*)d_in[2];
    const float* w_q   = (const float*)d_in[3];
    const float* w_k   = (const float*)d_in[4];
    const float* w_v   = (const float*)d_in[5];
    const float* w_mha = (const float*)d_in[6];
    const float* b_q   = (const float*)d_in[7];
    const float* b_k   = (const float*)d_in[8];
    const float* b_v   = (const float*)d_in[9];
    const float* b_mha = (const float*)d_in[10];

    const size_t T = (size_t)NB * NN * ND;  // 8388608
    short* ws  = (short*)d_ws;
    short* qp  = ws;
    short* kp  = qp + T;
    short* vpT = kp + T;
    short* dpa = vpT + T;
    short* Wt  = dpa + T;  // 4 * 262144 shorts

    Ptrs4 p;
    p.in[0] = w_q;   p.out[0] = Wt;
    p.in[1] = w_k;   p.out[1] = Wt + 262144;
    p.in[2] = w_v;   p.out[2] = Wt + 524288;
    p.in[3] = w_mha; p.out[3] = Wt + 786432;
    transpose_w<<<dim3(16, 16, 4), dim3(32, 8), 0, stream>>>(p);

    gemm_bt_bias<1, 0, 0><<<dim3(128, 4), 256, 0, stream>>>(q, Wt,          b_q, qp);
    gemm_bt_bias<1, 0, 0><<<dim3(128, 4), 256, 0, stream>>>(k, Wt + 262144, b_k, kp);
    gemm_bt_bias<1, 1, 0><<<dim3(128, 4), 256, 0, stream>>>(v, Wt + 524288, b_v, vpT);

    flash_attn<<<dim3(64, 4), 512, 0, stream>>>(qp, kp, vpT, dpa);

    gemm_bt_bias<0, 0, 1><<<dim3(128, 4), 256, 0, stream>>>(dpa, Wt + 786432, b_mha, d_out);
}

// Round 12
// 457.378 us; speedup vs baseline: 1.7747x; 1.0083x over previous
//
#include <hip/hip_runtime.h>
#include <hip/hip_bf16.h>

// MultiheadAttention (heads=1 due to reference bug): B=4, N=4096, D=512, PROJ=512.
// scale = 1/sqrt(64) = 0.125. Inputs fp32, output fp32, internal bf16 MFMA.
//
// Pipeline (4 launches on stream):
//  1. transpose_w           Wt[n][k] (bf16) = W[k][n] (fp32) for w_q,w_k,w_v,w_mha
//  2. proj_gemm3 (z=0,1,2)  qp/kp/vpT = bf16(q/k/v) @ W + b in ONE launch
//                           (z==2 uses the VT transposed epilogue)
//  3. flash_attn            dpa = softmax(qp kp^T * 0.125) @ vp
//  4. gemm<0,0,1>           out = dpa @ w_mha + b_mha -> d_out (FP32)
//
// R12 (from R11/R8 @461.2us, flash 278.0 verified): the 3 projection gemms were
// independent but stream-serialized (3 tails + 2 launch gaps). Merged into one
// grid (128,4,3) launch; body is the verified R8 AF32 gemm verbatim, epilogue
// branches block-uniformly on z==2 (VT). Flash and final gemm untouched.
// History: R9 32-key pipeline -27% (per-iter VALU doubled); R10 e-slice PV -56%
// (register spill, WRITE_SIZE 21->335MB); both reverted.
//
// ws layout (shorts): qp, kp, vpT, dpa (8388608 each), Wt (4*262144) = 69 MB.

typedef __attribute__((ext_vector_type(8))) short bf16x8;
typedef __attribute__((ext_vector_type(4))) float f32x4;

#define NB 4
#define NN 4096
#define ND 512

__device__ __forceinline__ f32x4 mfma16(bf16x8 a, bf16x8 b, f32x4 c) {
    return __builtin_amdgcn_mfma_f32_16x16x32_bf16(a, b, c, 0, 0, 0);
}
__device__ __forceinline__ short f2bf(float f) {
    __hip_bfloat16 h = __float2bfloat16(f);
    return *reinterpret_cast<short*>(&h);
}

typedef __attribute__((address_space(1))) const unsigned int gls_gt;
typedef __attribute__((address_space(3))) unsigned int gls_lt;
__device__ __forceinline__ void gll16(const void* g, void* l) {
    __builtin_amdgcn_global_load_lds((gls_gt*)g, (gls_lt*)l, 16, 0, 0);
}

// 16-lane-group reductions on the VALU pipe via DPP row_ror (DPP row = 16 lanes).
#define DPP_ROR_STEP(V, CTRL, OP)                                              \
    {                                                                          \
        int _t = __builtin_amdgcn_update_dpp(0, __float_as_int(V), (CTRL),     \
                                             0xf, 0xf, true);                  \
        (V) = OP((V), __int_as_float(_t));                                     \
    }
__device__ __forceinline__ float faddf(float a, float b) { return a + b; }
__device__ __forceinline__ float rmax16(float v) {
    DPP_ROR_STEP(v, 0x128, fmaxf)
    DPP_ROR_STEP(v, 0x124, fmaxf)
    DPP_ROR_STEP(v, 0x122, fmaxf)
    DPP_ROR_STEP(v, 0x121, fmaxf)
    return v;
}
__device__ __forceinline__ float rsum16(float v) {
    DPP_ROR_STEP(v, 0x128, faddf)
    DPP_ROR_STEP(v, 0x124, faddf)
    DPP_ROR_STEP(v, 0x122, faddf)
    DPP_ROR_STEP(v, 0x121, faddf)
    return v;
}

// ---------------- weight transpose: Wt[c][r] (bf16) = W[r][c] (fp32), 512x512 ----
struct Ptrs4 {
    const float* in[4];
    short* out[4];
};

__global__ void transpose_w(Ptrs4 p) {
    __shared__ short tile[32][33];
    const float* in = p.in[blockIdx.z];
    short* out = p.out[blockIdx.z];
    int r0 = blockIdx.y * 32, c0 = blockIdx.x * 32;
    int tx = threadIdx.x, ty = threadIdx.y;  // 32 x 8
    for (int i = 0; i < 32; i += 8)
        tile[ty + i][tx] = f2bf(in[(r0 + ty + i) * 512 + c0 + tx]);
    __syncthreads();
    for (int i = 0; i < 32; i += 8)
        out[(c0 + ty + i) * 512 + r0 + tx] = tile[tx][ty + i];
}

// ---------------- fused 3-projection GEMM: z selects q/k/v ----------------------
// Body = verified R8 AF32 gemm (128x128 tile, gll16 B-staging + reg-staged fp32
// A-cast, dbuf, 2 blocks/CU). Epilogue: z<2 -> [row][col] bf16 retile; z==2 ->
// VT per-batch transposed retile. Grid (128, 4, 3): x = m-tile (XCD locality),
// y = n-tile, z = projection. Blocks of different z overlap on the CUs.
struct ProjArgs {
    const float* in[3];
    const short* wt[3];
    const float* bias[3];
    short* out[3];
};

__global__ __launch_bounds__(256, 2) void proj_gemm3(ProjArgs pp) {
    __shared__ __align__(1024) char As[2][16384];
    __shared__ __align__(1024) char Bs[2][16384];
    int z = blockIdx.z;
    const float* A32 = pp.in[z];
    const short* Bt = pp.wt[z];
    const float* bias = pp.bias[z];
    short* C = pp.out[z];

    int tid = threadIdx.x;
    int lane = tid & 63, w = tid >> 6;
    int l15 = lane & 15, l4 = lane >> 4;
    int wr2 = (w & 1) * 64, wc2 = (w >> 1) * 64;
    int m0 = blockIdx.x * 128, n0 = blockIdx.y * 128;
    f32x4 acc[16] = {};  // [mi*4+ni]

    int sr = lane >> 3;
    int sd = ((lane & 7) ^ sr) << 3;  // swizzled k-offset in shorts (gll path)

#define P_STAGE_B(BUF, KT)                                                  \
    {                                                                       \
        _Pragma("unroll")                                                   \
        for (int i = 0; i < 4; i++) {                                       \
            int rbase = i * 32 + w * 8;                                     \
            gll16(&Bt[(size_t)(n0 + rbase + sr) * 512 + (KT) + sd],         \
                  Bs[BUF] + rbase * 128);                                   \
        }                                                                   \
    }

    float4 areg[8];
    int arow = w * 32 + (lane >> 4);
    int akc = lane & 15;
#define P_LOAD_A32(KT)                                                      \
    {                                                                       \
        _Pragma("unroll")                                                   \
        for (int inst = 0; inst < 8; inst++)                                \
            areg[inst] = ((const float4*)(A32 +                             \
                (size_t)(m0 + arow + inst * 4) * 512 + (KT)))[akc];         \
    }
#define P_WRITE_A32(BUF)                                                    \
    {                                                                       \
        _Pragma("unroll")                                                   \
        for (int inst = 0; inst < 8; inst++) {                              \
            int r = arow + inst * 4;                                        \
            short pk[4];                                                    \
            pk[0] = f2bf(areg[inst].x); pk[1] = f2bf(areg[inst].y);         \
            pk[2] = f2bf(areg[inst].z); pk[3] = f2bf(areg[inst].w);         \
            *(long long*)(As[BUF] + r * 128 +                               \
                (((akc >> 1) ^ (r & 7)) << 4) + ((akc & 1) << 3)) =         \
                *(const long long*)pk;                                      \
        }                                                                   \
    }

    P_LOAD_A32(0);
    P_STAGE_B(0, 0);
    P_WRITE_A32(0);
    for (int t = 0; t < 8; t++) {
        __syncthreads();                       // publishes buf[t&1]
        if (t < 7) {
            P_LOAD_A32((t + 1) * 64);
            P_STAGE_B((t + 1) & 1, (t + 1) * 64);
        }
        const char* Ab = As[t & 1];
        const char* Bb = Bs[t & 1];
#pragma unroll
        for (int kb = 0; kb < 2; kb++) {
            int ph = ((((kb << 2) | l4) ^ (l15 & 7)) << 4);
            bf16x8 af[4], bfr[4];
#pragma unroll
            for (int mi = 0; mi < 4; mi++)
                af[mi] = *(const bf16x8*)(Ab + (wr2 + mi * 16 + l15) * 128 + ph);
#pragma unroll
            for (int ni = 0; ni < 4; ni++)
                bfr[ni] = *(const bf16x8*)(Bb + (wc2 + ni * 16 + l15) * 128 + ph);
#pragma unroll
            for (int mi = 0; mi < 4; mi++)
#pragma unroll
                for (int ni = 0; ni < 4; ni++)
                    acc[mi * 4 + ni] = mfma16(af[mi], bfr[ni], acc[mi * 4 + ni]);
        }
        if (t < 7) P_WRITE_A32((t + 1) & 1);   // loads covered by MFMA phase
    }
#undef P_STAGE_B
#undef P_LOAD_A32
#undef P_WRITE_A32
    if (z == 2) {
        // VT: [col][row] bf16 tile in LDS (reuse As). b64 frag writes, XOR swz
        // (col&7)<<4 (16B-granular); bf16x8 coalesced stores along j.
        __syncthreads();
        short* Ct = (short*)As;
#pragma unroll
        for (int mi = 0; mi < 4; mi++)
#pragma unroll
            for (int ni = 0; ni < 4; ni++) {
                f32x4 vv = acc[mi * 4 + ni];
                int col = wc2 + ni * 16 + l15;
                float bv = bias[n0 + col];
                int r0w = wr2 + mi * 16 + l4 * 4;
                short pk[4];
#pragma unroll
                for (int r = 0; r < 4; r++) pk[r] = f2bf(vv[r] + bv);
                int byteoff = col * 256 + ((r0w * 2) ^ ((col & 7) << 4));
                *(long long*)((char*)Ct + byteoff) = *(const long long*)pk;
            }
        __syncthreads();
        int b = m0 >> 12;
        short* Cb = C + (size_t)b * (ND * NN) + (m0 & 4095);
#pragma unroll
        for (int s = 0; s < 8; s++) {
            int col = (tid >> 4) + 16 * s;
            int j = tid & 15;
            int byteoff = col * 256 + ((16 * j) ^ ((col & 7) << 4));
            bf16x8 vvv = *(const bf16x8*)((char*)Ct + byteoff);
            *(bf16x8*)(Cb + (size_t)(n0 + col) * NN + 8 * j) = vvv;
        }
    } else {
        // [row][col] bf16 tile in LDS; b16 writes, bf16x8 coalesced stores.
        __syncthreads();
        short* Ct = (short*)As;
#pragma unroll
        for (int mi = 0; mi < 4; mi++)
#pragma unroll
            for (int ni = 0; ni < 4; ni++) {
                f32x4 vv = acc[mi * 4 + ni];
                int col = wc2 + ni * 16 + l15;
                float bv = bias[n0 + col];
#pragma unroll
                for (int r = 0; r < 4; r++) {
                    int row = wr2 + mi * 16 + l4 * 4 + r;
                    int byteoff = row * 256 + ((col * 2) ^ ((row & 3) << 5));
                    *(short*)((char*)Ct + byteoff) = f2bf(vv[r] + bv);
                }
            }
        __syncthreads();
#pragma unroll
        for (int s = 0; s < 8; s++) {
            int row = (tid >> 4) + 16 * s;
            int j = tid & 15;
            int byteoff = row * 256 + ((16 * j) ^ ((row & 3) << 5));
            bf16x8 vvv = *(const bf16x8*)((char*)Ct + byteoff);
            *(bf16x8*)(C + (size_t)(m0 + row) * 512 + n0 + 8 * j) = vvv;
        }
    }
}

// ---------------- final GEMM (R8 template, AF32=0/OF32=1 path only) -------------
template <int AF32, int VT, int OF32>
__global__ __launch_bounds__(256, 2) void gemm_bt_bias(
    const void* __restrict__ Av, const short* __restrict__ Bt,
    const float* __restrict__ bias, void* __restrict__ C) {
    __shared__ __align__(1024) char As[2][16384];
    __shared__ __align__(1024) char Bs[2][16384];
    int tid = threadIdx.x;
    int lane = tid & 63, w = tid >> 6;
    int l15 = lane & 15, l4 = lane >> 4;
    int wr2 = (w & 1) * 64, wc2 = (w >> 1) * 64;
    int m0 = blockIdx.x * 128, n0 = blockIdx.y * 128;
    f32x4 acc[16] = {};  // [mi*4+ni]

    int sr = lane >> 3;
    int sd = ((lane & 7) ^ sr) << 3;  // swizzled k-offset in shorts (gll path)

#define STAGE_B(BUF, KT)                                                    \
    {                                                                       \
        _Pragma("unroll")                                                   \
        for (int i = 0; i < 4; i++) {                                       \
            int rbase = i * 32 + w * 8;                                     \
            gll16(&Bt[(size_t)(n0 + rbase + sr) * 512 + (KT) + sd],         \
                  Bs[BUF] + rbase * 128);                                   \
        }                                                                   \
    }
#define STAGE_A16(BUF, KT)                                                  \
    {                                                                       \
        const short* A16 = (const short*)Av;                                \
        _Pragma("unroll")                                                   \
        for (int i = 0; i < 4; i++) {                                       \
            int rbase = i * 32 + w * 8;                                     \
            gll16(&A16[(size_t)(m0 + rbase + sr) * 512 + (KT) + sd],        \
                  As[BUF] + rbase * 128);                                   \
        }                                                                   \
    }

    STAGE_A16(0, 0);
    STAGE_B(0, 0);
    for (int t = 0; t < 8; t++) {
        __syncthreads();                       // publishes buf[t&1]
        if (t < 7) {
            STAGE_A16((t + 1) & 1, (t + 1) * 64);
            STAGE_B((t + 1) & 1, (t + 1) * 64);
        }
        const char* Ab = As[t & 1];
        const char* Bb = Bs[t & 1];
#pragma unroll
        for (int kb = 0; kb < 2; kb++) {
            int ph = ((((kb << 2) | l4) ^ (l15 & 7)) << 4);
            bf16x8 af[4], bfr[4];
#pragma unroll
            for (int mi = 0; mi < 4; mi++)
                af[mi] = *(const bf16x8*)(Ab + (wr2 + mi * 16 + l15) * 128 + ph);
#pragma unroll
            for (int ni = 0; ni < 4; ni++)
                bfr[ni] = *(const bf16x8*)(Bb + (wc2 + ni * 16 + l15) * 128 + ph);
#pragma unroll
            for (int mi = 0; mi < 4; mi++)
#pragma unroll
                for (int ni = 0; ni < 4; ni++)
                    acc[mi * 4 + ni] = mfma16(af[mi], bfr[ni], acc[mi * 4 + ni]);
        }
    }
#undef STAGE_B
#undef STAGE_A16
    // fp32 output: scalar dword stores (64B segments per 16-lane group)
    for (int mi = 0; mi < 4; mi++)
        for (int ni = 0; ni < 4; ni++) {
            f32x4 vv = acc[mi * 4 + ni];
            int col = n0 + wc2 + ni * 16 + l15;
            float bv = bias[col];
            for (int r = 0; r < 4; r++) {
                int row = m0 + wr2 + mi * 16 + l4 * 4 + r;
                ((float*)C)[(size_t)row * 512 + col] = vv[r] + bv;
            }
        }
}

// ---------------- flash attention (R6/R8 structure, verified @276-278us) --------
// Block: 64 Q-rows of one batch, 512 threads (8 waves: wr 0..3 q-16-blocks x wc 0..1
// key/e-halves). Q persistent in regs. Full 64-key chunk staged per iteration.
// LDS 140 KB (1 block/CU): Ks 64x512 bf16 (slot^row&15), Vs 512x64 bf16 (slot^row&7),
// Pld 64x64 bf16 (slot^row&7), Sex stats. 3 barriers/iter, both stages prefetched.
__global__ __launch_bounds__(512, 2) void flash_attn(
    const short* __restrict__ qp, const short* __restrict__ kp,
    const short* __restrict__ vpT, short* __restrict__ dpa) {
    __shared__ __align__(1024) char KsB[65536];
    __shared__ __align__(1024) char VsB[65536];
    __shared__ __align__(16)   char PldB[8192];
    __shared__ float SexM[128];   // [wc][row] half-max
    __shared__ float SexS[128];   // [wc][row] half-sum

    int tid = threadIdx.x;
    int lane = tid & 63, w = tid >> 6;
    int l15 = lane & 15, l4 = lane >> 4;
    int wr = w & 3;    // q 16-row block
    int wc = w >> 2;   // key/e half
    int b = blockIdx.y;
    int q0 = blockIdx.x * 64;

    const short* qpb = qp + b * (NN * ND);
    const short* kpb = kp + b * (NN * ND);
    const short* vtb = vpT + b * (ND * NN);

    // persistent Q fragments: A-row = l15 (q-row q0+wr*16+l15), k = kb*32 + l4*8
    bf16x8 qf[16];
    {
        const short* qrow = qpb + (q0 + wr * 16 + l15) * ND + l4 * 8;
#pragma unroll
        for (int kb = 0; kb < 16; kb++) qf[kb] = *(const bf16x8*)(qrow + kb * 32);
    }
    f32x4 oacc[16] = {};
    float m_run[4], l_run[4];
#pragma unroll
    for (int r = 0; r < 4; r++) { m_run[r] = -1e30f; l_run[r] = 0.f; }

    // swizzled 16B-slot byte offsets for V/P reads (row&7 == l15&7 on all read rows)
    const int vsl0 = ((l4 ^ (l15 & 7)) << 4);
    const int vsl1 = vsl0 ^ 64;

    // K row r (1024B): physical slot p holds logical 16B chunk d = p ^ (r&15).
#define STAGE_K(J0)                                                         \
    {                                                                       \
        _Pragma("unroll")                                                   \
        for (int c = 0; c < 8; c++) {                                       \
            int key = w * 8 + c;                                            \
            const short* src = kpb + (size_t)((J0) + key) * ND +            \
                               ((lane ^ (key & 15)) << 3);                  \
            gll16(src, KsB + key * 1024);                                   \
        }                                                                   \
    }
    // V e-row (128B, 8 slots): slot p holds chunk p ^ (e&7). One gll = 8 e-rows.
#define STAGE_V(J0)                                                         \
    {                                                                       \
        _Pragma("unroll")                                                   \
        for (int c = 0; c < 8; c++) {                                       \
            int g = w * 8 + c;                                              \
            int e = g * 8 + (lane >> 3);                                    \
            const short* src = vtb + (size_t)e * NN + (J0) +                \
                               (((lane & 7) ^ (e & 7)) << 3);               \
            gll16(src, VsB + g * 1024);                                     \
        }                                                                   \
    }

    STAGE_K(0);
    STAGE_V(0);
    __syncthreads();

    for (int j0 = 0; j0 < NN; j0 += 64) {
        // ---- S = Q K^T : C[m=q (l4*4+r)][n=key (l15)], keys wc*32 + t*16 + l15 ----
        f32x4 s0 = {}, s1 = {};
        {
            const char* kb0 = KsB + (32 * wc + l15) * 1024;
            const char* kb1 = kb0 + 16 * 1024;
#pragma unroll
            for (int kb = 0; kb < 16; kb++) {
                int sl = ((((kb << 2) | l4) ^ l15) << 4);   // (key&15)==l15 for both tiles
                s0 = mfma16(qf[kb], *(const bf16x8*)(kb0 + sl), s0);
                s1 = mfma16(qf[kb], *(const bf16x8*)(kb1 + sl), s1);
            }
        }
        // ---- in-register half softmax stats (over this wc's 32 keys) ----
        // 16-lane reductions on VALU via DPP row_ror (no LDS traffic)
        float vv0[4], vv1[4], mx[4], ss[4], p0[4], p1[4];
#pragma unroll
        for (int r = 0; r < 4; r++) {
            vv0[r] = s0[r] * 0.125f;
            vv1[r] = s1[r] * 0.125f;
            mx[r] = rmax16(fmaxf(vv0[r], vv1[r]));
        }
#pragma unroll
        for (int r = 0; r < 4; r++) {
            p0[r] = __expf(vv0[r] - mx[r]);
            p1[r] = __expf(vv1[r] - mx[r]);
            ss[r] = rsum16(p0[r] + p1[r]);
        }
        int row4 = wr * 16 + l4 * 4;
        if (l15 == 0) {
#pragma unroll
            for (int r = 0; r < 4; r++) {
                SexM[wc * 64 + row4 + r] = mx[r];
                SexS[wc * 64 + row4 + r] = ss[r];
            }
        }
        __syncthreads();   // A: Sex visible; V(t) stage drained
        // ---- merge halves, running (m,l) update, write P bf16 ----
        float al4[4];
#pragma unroll
        for (int r = 0; r < 4; r++) {
            int row = row4 + r;
            float mo = SexM[(wc ^ 1) * 64 + row];
            float so = SexS[(wc ^ 1) * 64 + row];
            float mt = fmaxf(mx[r], mo);
            float st = ss[r] * __expf(mx[r] - mt) + so * __expf(mo - mt);
            float mn = fmaxf(m_run[r], mt);
            float al = __expf(m_run[r] - mn);
            l_run[r] = l_run[r] * al + st * __expf(mt - mn);
            m_run[r] = mn;
            al4[r] = al;
            float fs = __expf(mx[r] - mn);
            int rw7 = row & 7;
            char* prow = PldB + row * 128;
            int col0 = wc * 32 + l15;
            *(short*)(prow + (((col0 >> 3) ^ rw7) << 4) + ((col0 & 7) << 1)) = f2bf(p0[r] * fs);
            int col1 = col0 + 16;
            *(short*)(prow + (((col1 >> 3) ^ rw7) << 4) + ((col1 & 7) << 1)) = f2bf(p1[r] * fs);
        }
        // ---- O rescale, skipped when alpha==1 for all 16 rows of this wave
        // (exact: __expf(0)==1.0f when running max unchanged) ----
        {
            bool need = (al4[0] != 1.f) | (al4[1] != 1.f) |
                        (al4[2] != 1.f) | (al4[3] != 1.f);
            if (__any(need)) {
#pragma unroll
                for (int t = 0; t < 16; t++)
#pragma unroll
                    for (int r = 0; r < 4; r++) oacc[t][r] *= al4[r];
            }
        }
        __syncthreads();   // B: Pld visible
        if (j0 + 64 < NN) STAGE_K(j0 + 64);   // lands during PV, drains at barrier C
        // ---- O += P V ----
        bf16x8 pa0, pa1;
        {
            const char* prow = PldB + (wr * 16 + l15) * 128;
            pa0 = *(const bf16x8*)(prow + vsl0);   // keys 0..31  (chunk l4)
            pa1 = *(const bf16x8*)(prow + vsl1);   // keys 32..63 (chunk 4+l4)
        }
#pragma unroll
        for (int eh = 0; eh < 2; eh++) {
#pragma unroll
            for (int i = 0; i < 8; i++) {
                const char* vb = VsB + (eh * 256 + 32 * i + 16 * wc + l15) * 128;
                int oi = eh * 8 + i;
                oacc[oi] = mfma16(pa0, *(const bf16x8*)(vb + vsl0), oacc[oi]);
                oacc[oi] = mfma16(pa1, *(const bf16x8*)(vb + vsl1), oacc[oi]);
            }
        }
        __syncthreads();   // C: PV done; K(t+1) drained
        if (j0 + 64 < NN) STAGE_V(j0 + 64);   // lands during next QK^T, drains at A
    }
    // ---- finalize: O /= l, store dpa ----
    float li[4];
#pragma unroll
    for (int r = 0; r < 4; r++) li[r] = 1.f / l_run[r];
    short* dpb = dpa + b * (NN * ND);
#pragma unroll
    for (int eh = 0; eh < 2; eh++)
#pragma unroll
        for (int i = 0; i < 8; i++) {
            int col = (16 * eh + 2 * i + wc) * 16 + l15;
#pragma unroll
            for (int r = 0; r < 4; r++) {
                int row = q0 + wr * 16 + l4 * 4 + r;
                dpb[row * ND + col] = f2bf(oacc[eh * 8 + i][r] * li[r]);
            }
        }
}

extern "C" void kernel_launch(void* const* d_in, const int* in_sizes, int n_in,
                              void* d_out, int out_size, void* d_ws, size_t ws_size,
                              hipStream_t stream) {
    const float* q     = (const float*)d_in[0];
    const float* k     = (const float*)d_in[1];
    const float* v     = (const float*)d_in[2];
    const float* w_q   = (const float*)d_in[3];
    const float* w_k   = (const float*)d_in[4];
    const float* w_v   = (const float*)d_in[5];
    const float* w_mha = (const float*)d_in[6];
    const float* b_q   = (const float*)d_in[7];
    const float* b_k   = (const float*)d_in[8];
    const float* b_v   = (const float*)d_in[9];
    const float* b_mha = (const float*)d_in[10];

    const size_t T = (size_t)NB * NN * ND;  // 8388608
    short* ws  = (short*)d_ws;
    short* qp  = ws;
    short* kp  = qp + T;
    short* vpT = kp + T;
    short* dpa = vpT + T;
    short* Wt  = dpa + T;  // 4 * 262144 shorts

    Ptrs4 p;
    p.in[0] = w_q;   p.out[0] = Wt;
    p.in[1] = w_k;   p.out[1] = Wt + 262144;
    p.in[2] = w_v;   p.out[2] = Wt + 524288;
    p.in[3] = w_mha; p.out[3] = Wt + 786432;
    transpose_w<<<dim3(16, 16, 4), dim3(32, 8), 0, stream>>>(p);

    ProjArgs pa;
    pa.in[0] = q;  pa.wt[0] = Wt;          pa.bias[0] = b_q; pa.out[0] = qp;
    pa.in[1] = k;  pa.wt[1] = Wt + 262144; pa.bias[1] = b_k; pa.out[1] = kp;
    pa.in[2] = v;  pa.wt[2] = Wt + 524288; pa.bias[2] = b_v; pa.out[2] = vpT;
    proj_gemm3<<<dim3(128, 4, 3), 256, 0, stream>>>(pa);

    flash_attn<<<dim3(64, 4), 512, 0, stream>>>(qp, kp, vpT, dpa);

    gemm_bt_bias<0, 0, 1><<<dim3(128, 4), 256, 0, stream>>>(dpa, Wt + 786432, b_mha, d_out);
}